// Round 3
// baseline (3506.089 us; speedup 1.0000x reference)
//
#include <hip/hip_runtime.h>
#include <hip/hip_bf16.h>
#include <math.h>

// Problem constants
#define BQ    8
#define E     256
#define HW    1024               // 32*32
#define NTOK  8192               // BQ*HW
#define NE    16384
#define NSPLIT 8
#define CODES_PER_BLK (NE / NSPLIT)   // 2048
#define GBATCH 16

// ---------------------------------------------------------------------------
// Kernel 1: cnorm[n] = sum_k codebook[n][k]^2   (wave per row, float4 loads)
// ---------------------------------------------------------------------------
__global__ __launch_bounds__(256) void k_cnorm(const float* __restrict__ cb,
                                               float* __restrict__ cnorm) {
    const int wid  = threadIdx.x >> 6;
    const int lane = threadIdx.x & 63;
    const int row  = blockIdx.x * 4 + wid;
    const float4* r = (const float4*)(cb + (size_t)row * E);
    float4 v = r[lane];
    float s = v.x * v.x + v.y * v.y + v.z * v.z + v.w * v.w;
#pragma unroll
    for (int off = 32; off >= 1; off >>= 1) s += __shfl_xor(s, off, 64);
    if (lane == 0) cnorm[row] = s;
}

// ---------------------------------------------------------------------------
// Kernel 2: fused distance + running argmin over a code range.
// lane = token (64 tokens/block), wave w owns K-part [w*64, w*64+64).
// The x fragment is held in 64 NAMED scalar floats (macro-generated) --
// rounds 1-2 used float xr[64], which the compiler kept as a scratch alloca
// (VGPR_Count=64, WRITE_SIZE~300MB of spill traffic, 3.5ms). Named scalars
// are SSA values and cannot spill to an alloca.
// Codebook values come in via scalar loads (wave-uniform address) so the
// inner loop is pure v_fma_f32 with an SGPR operand -> ~zero LDS traffic.
// Partial dots for 16 codes are summed across the 4 waves through a
// double-buffered LDS tile with ONE barrier per 16 codes.
// ---------------------------------------------------------------------------
__global__ __launch_bounds__(256, 4) void k_argmin(
    const float* __restrict__ z, const float* __restrict__ cb,
    const float* __restrict__ cnorm,
    float* __restrict__ pmin, int* __restrict__ pidx)
{
    __shared__ float lds[8192];                 // 32 KB: two 4096-float buffers
    const int tid  = threadIdx.x;
    const int lane = tid & 63;
    const int wid  = __builtin_amdgcn_readfirstlane(tid >> 6); // force SGPR
    const int tile = blockIdx.x;                // 0..127  (token tile)
    const int ns   = blockIdx.y;                // 0..7    (code split)
    const int b    = tile >> 4;
    const int hw0  = (tile & 15) << 6;

    // ---- stage x straight into named registers ----------------------------
    // xr##k = z[b][wid*64+k][hw0+lane]; coalesced across lanes, constant k.
    const float* __restrict__ zp =
        z + (size_t)b * (E * HW) + (size_t)(wid * 64) * HW + hw0 + lane;
#define LD(k) const float xr##k = zp[(k) * HW];
    LD(0)  LD(1)  LD(2)  LD(3)  LD(4)  LD(5)  LD(6)  LD(7)
    LD(8)  LD(9)  LD(10) LD(11) LD(12) LD(13) LD(14) LD(15)
    LD(16) LD(17) LD(18) LD(19) LD(20) LD(21) LD(22) LD(23)
    LD(24) LD(25) LD(26) LD(27) LD(28) LD(29) LD(30) LD(31)
    LD(32) LD(33) LD(34) LD(35) LD(36) LD(37) LD(38) LD(39)
    LD(40) LD(41) LD(42) LD(43) LD(44) LD(45) LD(46) LD(47)
    LD(48) LD(49) LD(50) LD(51) LD(52) LD(53) LD(54) LD(55)
    LD(56) LD(57) LD(58) LD(59) LD(60) LD(61) LD(62) LD(63)
#undef LD

    float bmin = INFINITY;
    int   bidx = 0x7fffffff;
    const int n0 = ns * CODES_PER_BLK;
    const float* __restrict__ cbw = cb + (size_t)wid * 64;

    for (int batch = 0; batch < CODES_PER_BLK / GBATCH; ++batch) {
        float* buf = lds + (batch & 1) * 4096;
        const int nb = n0 + batch * GBATCH;

        // compute phase: partial dot over this wave's K-part, 16 codes
#pragma unroll 1
        for (int g = 0; g < GBATCH; ++g) {
            const float* __restrict__ cp = cbw + (size_t)(nb + g) * E;  // uniform -> s_load
            float a0 = 0.f, a1 = 0.f, a2 = 0.f, a3 = 0.f;
#define F4(k0,k1,k2,k3)                    \
            a0 = fmaf(xr##k0, cp[k0], a0); \
            a1 = fmaf(xr##k1, cp[k1], a1); \
            a2 = fmaf(xr##k2, cp[k2], a2); \
            a3 = fmaf(xr##k3, cp[k3], a3);
            F4(0,1,2,3)     F4(4,5,6,7)     F4(8,9,10,11)   F4(12,13,14,15)
            F4(16,17,18,19) F4(20,21,22,23) F4(24,25,26,27) F4(28,29,30,31)
            F4(32,33,34,35) F4(36,37,38,39) F4(40,41,42,43) F4(44,45,46,47)
            F4(48,49,50,51) F4(52,53,54,55) F4(56,57,58,59) F4(60,61,62,63)
#undef F4
            buf[wid * 1024 + g * 64 + lane] = (a0 + a1) + (a2 + a3);
        }
        __syncthreads();

        // reduce phase: wave `wid` handles codes g in [wid*4, wid*4+4)
#pragma unroll
        for (int i = 0; i < 4; ++i) {
            int g = wid * 4 + i;
            float v = buf[g * 64 + lane] + buf[1024 + g * 64 + lane]
                    + buf[2048 + g * 64 + lane] + buf[3072 + g * 64 + lane];
            float d = cnorm[nb + g] - 2.0f * v;   // |x|^2 dropped (argmin-invariant)
            int   n = nb + g;
            if (d < bmin) { bmin = d; bidx = n; } // ascending n -> keeps first min
        }
        // no barrier needed: double-buffered; next batch's barrier orders reuse
    }

    // ---- cross-wave (4 groups per token) final reduce ----------------------
    __syncthreads();
    lds[wid * 64 + lane] = bmin;
    ((int*)lds)[256 + wid * 64 + lane] = bidx;
    __syncthreads();
    if (tid < 64) {
        float m = lds[tid]; int mi = ((int*)lds)[256 + tid];
#pragma unroll
        for (int w = 1; w < 4; ++w) {
            float v = lds[w * 64 + tid]; int vi = ((int*)lds)[256 + w * 64 + tid];
            if (v < m || (v == m && vi < mi)) { m = v; mi = vi; }
        }
        int t = tile * 64 + tid;                // == b*1024 + hw0 + tid
        pmin[ns * NTOK + t] = m;
        pidx[ns * NTOK + t] = mi;
    }
}

// ---------------------------------------------------------------------------
// Kernel 3: reduce the NSPLIT partial (min,idx) pairs per token
// ---------------------------------------------------------------------------
__global__ __launch_bounds__(256) void k_pick(const float* __restrict__ pmin,
                                              const int* __restrict__ pidx,
                                              int* __restrict__ idxf) {
    int t = blockIdx.x * 256 + threadIdx.x;     // 0..8191
    float m = pmin[t]; int mi = pidx[t];
#pragma unroll
    for (int s = 1; s < NSPLIT; ++s) {
        float v = pmin[(size_t)s * NTOK + t]; int vi = pidx[(size_t)s * NTOK + t];
        if (v < m || (v == m && vi < mi)) { m = v; mi = vi; }
    }
    idxf[t] = mi;
}

// ---------------------------------------------------------------------------
// Kernel 4: gather codebook rows -> out[B,E,H,W], LDS transpose (pad 257).
// Both global sides coalesced; LDS reads/writes conflict-free.
// out = x + (x_q - x), mimicking the reference's straight-through arithmetic.
// ---------------------------------------------------------------------------
__global__ __launch_bounds__(256) void k_out(const float* __restrict__ z,
                                             const float* __restrict__ cb,
                                             const int* __restrict__ idxf,
                                             float* __restrict__ out) {
    __shared__ float xq[32 * 257];
    const int tid  = threadIdx.x;
    const int tile = blockIdx.x;                // 0..255
    const int b    = tile >> 5;
    const int hw0  = (tile & 31) << 5;          // 32 tokens per block
#pragma unroll
    for (int r = 0; r < 32; ++r) {
        int code = idxf[b * HW + hw0 + r];      // uniform -> s_load
        xq[r * 257 + tid] = cb[(size_t)code * E + tid];   // coalesced over e
    }
    __syncthreads();
    const int grp = tid >> 5, l = tid & 31;     // l = token row, grp = e-octant
#pragma unroll
    for (int j = 0; j < 32; ++j) {
        int e = grp * 32 + j;
        size_t o = (size_t)b * (E * HW) + (size_t)e * HW + hw0 + l;
        float x = z[o];
        out[o] = x + (xq[l * 257 + e] - x);
    }
}

// ---------------------------------------------------------------------------
extern "C" void kernel_launch(void* const* d_in, const int* in_sizes, int n_in,
                              void* d_out, int out_size, void* d_ws, size_t ws_size,
                              hipStream_t stream) {
    const float* z  = (const float*)d_in[0];    // [8,256,32,32]
    const float* cb = (const float*)d_in[1];    // [16384,256]
    float* out = (float*)d_out;

    float* ws    = (float*)d_ws;
    float* cnorm = ws;                                   // 16384 f
    float* pmin  = ws + NE;                              // NSPLIT*NTOK f
    int*   pidx  = (int*)(ws + NE + NSPLIT * NTOK);      // NSPLIT*NTOK i
    int*   idxf  = (int*)(ws + NE + 2 * NSPLIT * NTOK);  // NTOK i
    // total ws: (16384 + 65536 + 65536 + 8192)*4 B ~= 608 KB

    k_cnorm <<<NE / 4, 256, 0, stream>>>(cb, cnorm);
    k_argmin<<<dim3(NTOK / 64, NSPLIT), 256, 0, stream>>>(z, cb, cnorm, pmin, pidx);
    k_pick  <<<NTOK / 256, 256, 0, stream>>>(pmin, pidx, idxf);
    k_out   <<<NTOK / 32, 256, 0, stream>>>(z, cb, idxf, out);
}

// Round 4
// 1098.866 us; speedup vs baseline: 3.1906x; 3.1906x over previous
//
#include <hip/hip_runtime.h>
#include <math.h>

// Problem constants
#define E     256
#define HW    1024               // 32*32
#define NTOK  8192               // B*H*W
#define NE    16384
#define TM    128                // tokens per block tile
#define TN    128                // codes per chunk
#define BK    32                 // K slice
#define NCHUNK 8                 // code chunks per block -> 1024 codes/block
#define CODES_PER_BLOCK (TN * NCHUNK)

// ---------------------------------------------------------------------------
// Kernel 1: cnorm[n] = sum_k codebook[n][k]^2   (wave per row, float4 loads)
// ---------------------------------------------------------------------------
__global__ __launch_bounds__(256) void k_cnorm(const float* __restrict__ cb,
                                               float* __restrict__ cnorm) {
    const int wid  = threadIdx.x >> 6;
    const int lane = threadIdx.x & 63;
    const int row  = blockIdx.x * 4 + wid;
    const float4* r = (const float4*)(cb + (size_t)row * E);
    float4 v = r[lane];
    float s = v.x * v.x + v.y * v.y + v.z * v.z + v.w * v.w;
#pragma unroll
    for (int off = 32; off >= 1; off >>= 1) s += __shfl_xor(s, off, 64);
    if (lane == 0) cnorm[row] = s;
}

// ---------------------------------------------------------------------------
// Kernel 1b: init per-token argmin keys to +inf
// ---------------------------------------------------------------------------
__global__ __launch_bounds__(256) void k_init(unsigned long long* __restrict__ keys) {
    keys[blockIdx.x * 256 + threadIdx.x] = ~0ull;
}

// float -> order-preserving uint32 (no NaNs here)
__device__ __forceinline__ unsigned int f2key(float f) {
    unsigned int u = __float_as_uint(f);
    return (u & 0x80000000u) ? ~u : (u | 0x80000000u);
}

// ---------------------------------------------------------------------------
// Kernel 2: tiled distance + argmin. Canonical register-blocked GEMM shape:
// per-thread 8x8 FMA micro-tile (accumulators are non-rematerializable, so
// the allocator MUST keep them in VGPRs -- rounds 1-3's x-in-registers
// design was silently remat/spilled: VGPR=64, 300MB scratch writes, 3.5ms).
// A = z tile in LDS as [k][token]; B = codebook transposed on store to
// [k][code]. 64 FMA per 4 ds_read_b128 per k-step. Distances are reduced to
// a running per-token (min,idx), then one u64 atomicMin per token per block:
// key = (sortable(dist) << 32) | idx, so ties pick the lowest index --
// matching numpy's first-argmin. d = cnorm - 2*dot (|x|^2 argmin-invariant;
// 2*dot exact, single rounding -- same arithmetic that passed rounds 1-3).
// ---------------------------------------------------------------------------
__global__ __launch_bounds__(256, 4) void k_dist(
    const float* __restrict__ z, const float* __restrict__ cb,
    const float* __restrict__ cnorm, unsigned long long* __restrict__ keys)
{
    __shared__ __align__(16) float As[BK][TM];   // 16 KB
    __shared__ __align__(16) float Bs[BK][TN];   // 16 KB

    const int tid = threadIdx.x;
    const int tx  = tid & 15;            // token group: tokens tx*8..+8
    const int ty  = tid >> 4;            // code group:  codes  ty*8..+8
    const int token0 = blockIdx.x * TM;  // tile is within one image (1024/128)
    const int bimg   = token0 >> 10;
    const int hw0    = token0 & 1023;
    const int n00    = blockIdx.y * CODES_PER_BLOCK;

    const float* __restrict__ zbase = z + (size_t)bimg * (E * HW) + hw0;

    float bmin[8];
    int   bidx[8];
#pragma unroll
    for (int i = 0; i < 8; ++i) { bmin[i] = INFINITY; bidx[i] = 0; }

    for (int c = 0; c < NCHUNK; ++c) {
        const int n0 = n00 + c * TN;
        float acc[8][8];
#pragma unroll
        for (int i = 0; i < 8; ++i)
#pragma unroll
            for (int j = 0; j < 8; ++j) acc[i][j] = 0.f;

        for (int kc = 0; kc < E / BK; ++kc) {
            const int k0 = kc * BK;
            // ---- stage A: z[k0..+32][hw0..+128] -> As[k][tok] (coalesced) --
#pragma unroll
            for (int i = 0; i < 4; ++i) {
                int idx = tid + 256 * i;            // 0..1023
                int k   = idx >> 5;                 // 0..31
                int t4  = (idx & 31) << 2;          // 0,4,..,124
                *(float4*)&As[k][t4] =
                    *(const float4*)(zbase + (size_t)(k0 + k) * HW + t4);
            }
            // ---- stage B: cb[n0..+128][k0..+32] -> Bs[k][n] (transpose) ----
#pragma unroll
            for (int i = 0; i < 4; ++i) {
                int idx = tid + 256 * i;
                int n   = idx >> 3;                 // 0..127
                int kg  = (idx & 7) << 2;           // 0,4,..,28
                float4 v = *(const float4*)(cb + (size_t)(n0 + n) * E + k0 + kg);
                Bs[kg + 0][n] = v.x; Bs[kg + 1][n] = v.y;
                Bs[kg + 2][n] = v.z; Bs[kg + 3][n] = v.w;
            }
            __syncthreads();
            // ---- 8x8 micro-tile FMA over this K slice ----------------------
#pragma unroll 4
            for (int kk = 0; kk < BK; ++kk) {
                float4 a0 = *(const float4*)&As[kk][tx * 8];
                float4 a1 = *(const float4*)&As[kk][tx * 8 + 4];
                float4 b0 = *(const float4*)&Bs[kk][ty * 8];
                float4 b1 = *(const float4*)&Bs[kk][ty * 8 + 4];
                float av[8] = {a0.x, a0.y, a0.z, a0.w, a1.x, a1.y, a1.z, a1.w};
                float bv[8] = {b0.x, b0.y, b0.z, b0.w, b1.x, b1.y, b1.z, b1.w};
#pragma unroll
                for (int i = 0; i < 8; ++i)
#pragma unroll
                    for (int j = 0; j < 8; ++j)
                        acc[i][j] = fmaf(av[i], bv[j], acc[i][j]);
            }
            __syncthreads();
        }
        // ---- chunk epilogue: d = cnorm - 2*dot, running (min,idx) ----------
#pragma unroll
        for (int j = 0; j < 8; ++j) {
            int   n  = n0 + ty * 8 + j;
            float cn = cnorm[n];
#pragma unroll
            for (int i = 0; i < 8; ++i) {
                float d = fmaf(-2.f, acc[i][j], cn);   // == cn - 2*dot, 1 rounding
                if (d < bmin[i]) { bmin[i] = d; bidx[i] = n; }
            }
        }
    }

    // ---- cross-thread reduce over ty, then one atomicMin per token --------
    __syncthreads();
    unsigned long long* lk = (unsigned long long*)&As[0][0];   // 128*16 u64 = 16KB
#pragma unroll
    for (int i = 0; i < 8; ++i) {
        unsigned long long key =
            ((unsigned long long)f2key(bmin[i]) << 32) | (unsigned int)bidx[i];
        lk[(tx * 8 + i) * 16 + ty] = key;
    }
    __syncthreads();
    if (tid < 128) {
        unsigned long long m = lk[tid * 16];
#pragma unroll
        for (int t = 1; t < 16; ++t) {
            unsigned long long v = lk[tid * 16 + t];
            m = (v < m) ? v : m;
        }
        atomicMin(&keys[token0 + tid], m);
    }
}

// ---------------------------------------------------------------------------
// Kernel 3: gather codebook rows -> out[B,E,H,W], LDS transpose (pad 257).
// ---------------------------------------------------------------------------
__global__ __launch_bounds__(256) void k_out(const float* __restrict__ z,
                                             const float* __restrict__ cb,
                                             const unsigned long long* __restrict__ keys,
                                             float* __restrict__ out) {
    __shared__ float xq[32 * 257];
    const int tid  = threadIdx.x;
    const int tile = blockIdx.x;                // 0..255
    const int b    = tile >> 5;
    const int hw0  = (tile & 31) << 5;          // 32 tokens per block
#pragma unroll
    for (int r = 0; r < 32; ++r) {
        int code = (int)(keys[b * HW + hw0 + r] & 0xffffffffull);  // uniform
        xq[r * 257 + tid] = cb[(size_t)code * E + tid];            // coalesced
    }
    __syncthreads();
    const int grp = tid >> 5, l = tid & 31;     // l = token row, grp = e-octant
#pragma unroll
    for (int j = 0; j < 32; ++j) {
        int e = grp * 32 + j;
        size_t o = (size_t)b * (E * HW) + (size_t)e * HW + hw0 + l;
        float x = z[o];
        out[o] = x + (xq[l * 257 + e] - x);
    }
}

// ---------------------------------------------------------------------------
extern "C" void kernel_launch(void* const* d_in, const int* in_sizes, int n_in,
                              void* d_out, int out_size, void* d_ws, size_t ws_size,
                              hipStream_t stream) {
    const float* z  = (const float*)d_in[0];    // [8,256,32,32]
    const float* cb = (const float*)d_in[1];    // [16384,256]
    float* out = (float*)d_out;

    float* ws = (float*)d_ws;
    float* cnorm = ws;                                      // 16384 f = 64 KB
    unsigned long long* keys = (unsigned long long*)(ws + NE);  // 8192 u64 = 64 KB

    k_cnorm<<<NE / 4, 256, 0, stream>>>(cb, cnorm);
    k_init <<<NTOK / 256, 256, 0, stream>>>(keys);
    k_dist <<<dim3(NTOK / TM, NE / CODES_PER_BLOCK), 256, 0, stream>>>(z, cb, cnorm, keys);
    k_out  <<<NTOK / 32, 256, 0, stream>>>(z, cb, keys, out);
}

// Round 6
// 538.651 us; speedup vs baseline: 6.5090x; 2.0400x over previous
//
#include <hip/hip_runtime.h>
#include <hip/hip_fp16.h>
#include <math.h>

// Problem constants
#define E     256
#define HW    1024               // 32*32
#define NTOK  8192               // B*H*W
#define NE    16384
#define K2    512                // row layout: [hi(256) | lo'(256)], lo' = (x-hi)*2^12

typedef __attribute__((ext_vector_type(8))) _Float16 f16x8;
typedef __attribute__((ext_vector_type(4))) float    f32x4;

typedef __attribute__((address_space(3))) unsigned int       as3_u32;
typedef const __attribute__((address_space(1))) unsigned int as1_u32;

// async 16B/lane global->LDS: LDS dest = wave-uniform base + lane*16
static __device__ __forceinline__ void async_cp16(const void* g, void* l) {
    __builtin_amdgcn_global_load_lds((as1_u32*)g, (as3_u32*)l, 16, 0, 0);
}

// float -> order-preserving uint32 (no NaNs here)
__device__ __forceinline__ unsigned int f2key(float f) {
    unsigned int u = __float_as_uint(f);
    return (u & 0x80000000u) ? ~u : (u | 0x80000000u);
}

// ---------------------------------------------------------------------------
// Kernel 1: codebook prep. Wave per row: cnorm[n] = sum(c^2) (fp32), and
// split row: B2[n][k]=hi(c_k), B2[n][256+k]=f16((c_k-hi)*4096), K-contiguous.
// ---------------------------------------------------------------------------
__global__ __launch_bounds__(256) void k_prep_cb(const float* __restrict__ cb,
                                                 unsigned short* __restrict__ B2,
                                                 float* __restrict__ cnorm) {
    const int wid  = threadIdx.x >> 6;
    const int lane = threadIdx.x & 63;
    const int row  = blockIdx.x * 4 + wid;
    float4 v = *(const float4*)(cb + (size_t)row * E + lane * 4);
    float s = v.x * v.x + v.y * v.y + v.z * v.z + v.w * v.w;
#pragma unroll
    for (int off = 32; off >= 1; off >>= 1) s += __shfl_xor(s, off, 64);
    if (lane == 0) cnorm[row] = s;

    __half hx = __float2half(v.x), hy = __float2half(v.y),
           hz = __float2half(v.z), hw = __float2half(v.w);
    __half lx = __float2half((v.x - __half2float(hx)) * 4096.f);
    __half ly = __float2half((v.y - __half2float(hy)) * 4096.f);
    __half lz = __float2half((v.z - __half2float(hz)) * 4096.f);
    __half lw = __float2half((v.w - __half2float(hw)) * 4096.f);
    ushort4 hi4 = {__half_as_ushort(hx), __half_as_ushort(hy),
                   __half_as_ushort(hz), __half_as_ushort(hw)};
    ushort4 lo4 = {__half_as_ushort(lx), __half_as_ushort(ly),
                   __half_as_ushort(lz), __half_as_ushort(lw)};
    *(ushort4*)(B2 + (size_t)row * K2 + lane * 4)       = hi4;   // coalesced
    *(ushort4*)(B2 + (size_t)row * K2 + 256 + lane * 4) = lo4;
}

// ---------------------------------------------------------------------------
// Kernel 2: z prep with transpose. z[b][e][hw] fp32 -> A2[m=b*1024+hw][k]:
// hi at k=e, lo' at k=256+e. 64hw x 64e tile through padded LDS.
// ---------------------------------------------------------------------------
__global__ __launch_bounds__(256) void k_prep_z(const float* __restrict__ z,
                                                unsigned short* __restrict__ A2) {
    __shared__ float lds[64 * 65];
    const int tid = threadIdx.x;
    const int hw0 = blockIdx.x * 64;
    const int e0  = blockIdx.y * 64;
    const int b   = blockIdx.z;
#pragma unroll
    for (int r = 0; r < 16; ++r) {
        int e  = e0 + r * 4 + (tid >> 6);
        int hw = hw0 + (tid & 63);
        lds[(tid & 63) * 65 + r * 4 + (tid >> 6)] =
            z[((size_t)b * E + e) * HW + hw];
    }
    __syncthreads();
    const int row = tid & 63;          // hw within tile
    const int q   = tid >> 6;          // 16-col group
    const size_t m = (size_t)b * HW + hw0 + row;
    unsigned short* __restrict__ ph = A2 + m * K2 + e0 + q * 16;
    unsigned short* __restrict__ pl = ph + 256;
    ushort4 hbuf[4], lbuf[4];
#pragma unroll
    for (int g = 0; g < 4; ++g) {
        float v0 = lds[row * 65 + q * 16 + g * 4 + 0];
        float v1 = lds[row * 65 + q * 16 + g * 4 + 1];
        float v2 = lds[row * 65 + q * 16 + g * 4 + 2];
        float v3 = lds[row * 65 + q * 16 + g * 4 + 3];
        __half h0 = __float2half(v0), h1 = __float2half(v1),
               h2 = __float2half(v2), h3 = __float2half(v3);
        hbuf[g] = (ushort4){__half_as_ushort(h0), __half_as_ushort(h1),
                            __half_as_ushort(h2), __half_as_ushort(h3)};
        __half l0 = __float2half((v0 - __half2float(h0)) * 4096.f);
        __half l1 = __float2half((v1 - __half2float(h1)) * 4096.f);
        __half l2 = __float2half((v2 - __half2float(h2)) * 4096.f);
        __half l3 = __float2half((v3 - __half2float(h3)) * 4096.f);
        lbuf[g] = (ushort4){__half_as_ushort(l0), __half_as_ushort(l1),
                            __half_as_ushort(l2), __half_as_ushort(l3)};
    }
#pragma unroll
    for (int g = 0; g < 4; ++g) {
        *(ushort4*)(ph + g * 4) = hbuf[g];
        *(ushort4*)(pl + g * 4) = lbuf[g];
    }
}

// ---------------------------------------------------------------------------
// Kernel 2b: init per-token argmin keys to +inf
// ---------------------------------------------------------------------------
__global__ __launch_bounds__(256) void k_init(unsigned long long* __restrict__ keys) {
    keys[blockIdx.x * 256 + threadIdx.x] = ~0ull;
}

// ---------------------------------------------------------------------------
// Kernel 3: dual-accumulator split-f16 MFMA distance GEMM + argmin.
// dot = S1 + 2^-12 * S2, with S1 = hi_a.hi_b and S2 = hi_a.lo'_b + lo'_a.hi_b
// (lo' pre-scaled by 2^12 so all f16 values are normal -- no denorm flush).
// Round 5's single-GEMM [hi|lo].[hi|lo] dropped the cross terms (error ~1e-2,
// ~15 argmin flips, absmax 5.0). This restores them at 1.5x MFMA cost.
// Structure per K-slice (64 halves of E): stage Ah/Al/Bh/Bl 128x64 tiles via
// global_load_lds w16; 2 barriers; per wave 2 k-steps x (16+16+16) MFMAs.
// Epilogue: d = fma(-2, dot, cnorm[n]); u64 key = (sortable(d)<<32)|n;
// shfl_xor min over 16-lane col group; one atomicMin per token per block
// (ties -> lowest index == numpy first-argmin).
// ---------------------------------------------------------------------------
__global__ __launch_bounds__(256) void k_mfma(
    const unsigned short* __restrict__ A2, const unsigned short* __restrict__ B2,
    const float* __restrict__ cnorm, unsigned long long* __restrict__ keys)
{
    __shared__ __align__(16) unsigned short Ah[128 * 64];   // 16 KB each
    __shared__ __align__(16) unsigned short Al[128 * 64];
    __shared__ __align__(16) unsigned short Bh[128 * 64];
    __shared__ __align__(16) unsigned short Bl[128 * 64];

    const int tid  = threadIdx.x;
    const int lane = tid & 63;
    const int wave = __builtin_amdgcn_readfirstlane(tid >> 6);
    const int m0 = blockIdx.x * 128;
    const int n0 = blockIdx.y * 128;
    const int wm = (wave >> 1) * 64;     // wave's row block
    const int wn = (wave & 1) * 64;      // wave's col block

    const int srow  = (lane >> 3);       // staging sub-row 0..7
    const int schnk = (lane & 7) * 16;   // staging byte chunk in row

    f32x4 acc1[4][4], acc2[4][4];
#pragma unroll
    for (int i = 0; i < 4; ++i)
#pragma unroll
        for (int j = 0; j < 4; ++j) {
            acc1[i][j] = (f32x4){0.f, 0.f, 0.f, 0.f};
            acc2[i][j] = (f32x4){0.f, 0.f, 0.f, 0.f};
        }

    for (int kc = 0; kc < 4; ++kc) {     // four 64-half slices of E=256
        const int kb = kc * 128;         // byte offset of hi slice in a row
        // ---- stage Ah/Al/Bh/Bl: 16 wave-instrs, 8 rows each ---------------
#pragma unroll
        for (int t = 0; t < 4; ++t) {
            int r = wave * 32 + t * 8 + srow;
            const char* arow = (const char*)A2 + (size_t)(m0 + r) * 1024;
            const char* brow = (const char*)B2 + (size_t)(n0 + r) * 1024;
            char* dst = (char*)0 + wave * 4096 + t * 1024;   // offset only
            async_cp16(arow + kb + schnk,        (char*)Ah + (size_t)dst);
            async_cp16(arow + 512 + kb + schnk,  (char*)Al + (size_t)dst);
            async_cp16(brow + kb + schnk,        (char*)Bh + (size_t)dst);
            async_cp16(brow + 512 + kb + schnk,  (char*)Bl + (size_t)dst);
        }
        __syncthreads();                 // compiler drains vmcnt before barrier
        // ---- 2 MFMA k-steps over the 64-half slice ------------------------
#pragma unroll
        for (int kk = 0; kk < 2; ++kk) {
            const int ko = kk * 32 + (lane >> 4) * 8;   // frag k-offset
            f16x8 ah[4], al[4], bh[4], bl[4];
#pragma unroll
            for (int i = 0; i < 4; ++i) {
                int ra = (wm + i * 16 + (lane & 15)) * 64 + ko;
                ah[i] = *(const f16x8*)&Ah[ra];
                al[i] = *(const f16x8*)&Al[ra];
            }
#pragma unroll
            for (int j = 0; j < 4; ++j) {
                int rb = (wn + j * 16 + (lane & 15)) * 64 + ko;
                bh[j] = *(const f16x8*)&Bh[rb];
                bl[j] = *(const f16x8*)&Bl[rb];
            }
#pragma unroll
            for (int i = 0; i < 4; ++i)
#pragma unroll
                for (int j = 0; j < 4; ++j) {
                    acc1[i][j] = __builtin_amdgcn_mfma_f32_16x16x32_f16(
                        ah[i], bh[j], acc1[i][j], 0, 0, 0);
                    acc2[i][j] = __builtin_amdgcn_mfma_f32_16x16x32_f16(
                        ah[i], bl[j], acc2[i][j], 0, 0, 0);
                    acc2[i][j] = __builtin_amdgcn_mfma_f32_16x16x32_f16(
                        al[i], bh[j], acc2[i][j], 0, 0, 0);
                }
        }
        __syncthreads();
    }

    // ---- epilogue: per-row argmin, C/D layout col=lane&15, row=quad*4+reg --
#pragma unroll
    for (int i = 0; i < 4; ++i) {
#pragma unroll
        for (int r = 0; r < 4; ++r) {
            int token = m0 + wm + i * 16 + ((lane >> 4) << 2) + r;
            unsigned long long best = ~0ull;
#pragma unroll
            for (int j = 0; j < 4; ++j) {
                int n = n0 + wn + j * 16 + (lane & 15);
                float dot = fmaf(acc2[i][j][r], 0x1p-12f, acc1[i][j][r]);
                float d   = fmaf(-2.f, dot, cnorm[n]);
                unsigned long long key =
                    ((unsigned long long)f2key(d) << 32) | (unsigned int)n;
                best = key < best ? key : best;
            }
#pragma unroll
            for (int off = 1; off < 16; off <<= 1) {
                unsigned long long o = __shfl_xor(best, off, 64);
                best = o < best ? o : best;
            }
            if ((lane & 15) == 0) atomicMin(&keys[token], best);
        }
    }
}

// ---------------------------------------------------------------------------
// Kernel 4: gather codebook rows -> out[B,E,H,W], LDS transpose (pad 257).
// ---------------------------------------------------------------------------
__global__ __launch_bounds__(256) void k_out(const float* __restrict__ z,
                                             const float* __restrict__ cb,
                                             const unsigned long long* __restrict__ keys,
                                             float* __restrict__ out) {
    __shared__ float xq[32 * 257];
    const int tid  = threadIdx.x;
    const int tile = blockIdx.x;                // 0..255
    const int b    = tile >> 5;
    const int hw0  = (tile & 31) << 5;          // 32 tokens per block
#pragma unroll
    for (int r = 0; r < 32; ++r) {
        int code = (int)(keys[b * HW + hw0 + r] & 0xffffffffull);  // uniform
        xq[r * 257 + tid] = cb[(size_t)code * E + tid];            // coalesced
    }
    __syncthreads();
    const int grp = tid >> 5, l = tid & 31;
#pragma unroll
    for (int j = 0; j < 32; ++j) {
        int e = grp * 32 + j;
        size_t o = (size_t)b * (E * HW) + (size_t)e * HW + hw0 + l;
        float x = z[o];
        out[o] = x + (xq[l * 257 + e] - x);
    }
}

// ---------------------------------------------------------------------------
extern "C" void kernel_launch(void* const* d_in, const int* in_sizes, int n_in,
                              void* d_out, int out_size, void* d_ws, size_t ws_size,
                              hipStream_t stream) {
    const float* z  = (const float*)d_in[0];    // [8,256,32,32]
    const float* cb = (const float*)d_in[1];    // [16384,256]
    float* out = (float*)d_out;

    // workspace layout (bytes):
    //   A2   : 8192*512*2  = 8 MB   @ 0
    //   B2   : 16384*512*2 = 16 MB  @ 8M
    //   cnorm: 64 KB                @ 24M
    //   keys : 64 KB                @ 24M+64K
    char* ws = (char*)d_ws;
    unsigned short* A2 = (unsigned short*)ws;
    unsigned short* B2 = (unsigned short*)(ws + (size_t)NTOK * K2 * 2);
    float* cnorm = (float*)(ws + (size_t)NTOK * K2 * 2 + (size_t)NE * K2 * 2);
    unsigned long long* keys = (unsigned long long*)((char*)cnorm + NE * 4);

    k_prep_cb<<<NE / 4, 256, 0, stream>>>(cb, B2, cnorm);
    k_prep_z <<<dim3(16, 4, 8), 256, 0, stream>>>(z, A2);
    k_init   <<<NTOK / 256, 256, 0, stream>>>(keys);
    k_mfma   <<<dim3(NTOK / 128, NE / 128), 256, 0, stream>>>(A2, B2, cnorm, keys);
    k_out    <<<NTOK / 32, 256, 0, stream>>>(z, cb, keys, out);
}

// Round 7
// 505.259 us; speedup vs baseline: 6.9392x; 1.0661x over previous
//
#include <hip/hip_runtime.h>
#include <hip/hip_fp16.h>
#include <math.h>

// Problem constants
#define E     256
#define HW    1024               // 32*32
#define NTOK  8192               // B*H*W
#define NE    16384
#define K2    512                // row layout: [hi(256) | lo'(256)], lo' = (x-hi)*2^12

typedef __attribute__((ext_vector_type(8))) _Float16 f16x8;
typedef __attribute__((ext_vector_type(4))) float    f32x4;

typedef __attribute__((address_space(3))) unsigned int       as3_u32;
typedef const __attribute__((address_space(1))) unsigned int as1_u32;

// async 16B/lane global->LDS: LDS dest = wave-uniform base + lane*16
static __device__ __forceinline__ void async_cp16(const void* g, void* l) {
    __builtin_amdgcn_global_load_lds((as1_u32*)g, (as3_u32*)l, 16, 0, 0);
}

// float -> order-preserving uint32 (no NaNs here)
__device__ __forceinline__ unsigned int f2key(float f) {
    unsigned int u = __float_as_uint(f);
    return (u & 0x80000000u) ? ~u : (u | 0x80000000u);
}

// ---------------------------------------------------------------------------
// Kernel 1: codebook prep. Wave per row: cnorm[n] = sum(c^2) (fp32), and
// split row: B2[n][k]=hi(c_k), B2[n][256+k]=f16((c_k-hi)*4096), K-contiguous.
// ---------------------------------------------------------------------------
__global__ __launch_bounds__(256) void k_prep_cb(const float* __restrict__ cb,
                                                 unsigned short* __restrict__ B2,
                                                 float* __restrict__ cnorm) {
    const int wid  = threadIdx.x >> 6;
    const int lane = threadIdx.x & 63;
    const int row  = blockIdx.x * 4 + wid;
    float4 v = *(const float4*)(cb + (size_t)row * E + lane * 4);
    float s = v.x * v.x + v.y * v.y + v.z * v.z + v.w * v.w;
#pragma unroll
    for (int off = 32; off >= 1; off >>= 1) s += __shfl_xor(s, off, 64);
    if (lane == 0) cnorm[row] = s;

    __half hx = __float2half(v.x), hy = __float2half(v.y),
           hz = __float2half(v.z), hw = __float2half(v.w);
    __half lx = __float2half((v.x - __half2float(hx)) * 4096.f);
    __half ly = __float2half((v.y - __half2float(hy)) * 4096.f);
    __half lz = __float2half((v.z - __half2float(hz)) * 4096.f);
    __half lw = __float2half((v.w - __half2float(hw)) * 4096.f);
    ushort4 hi4 = {__half_as_ushort(hx), __half_as_ushort(hy),
                   __half_as_ushort(hz), __half_as_ushort(hw)};
    ushort4 lo4 = {__half_as_ushort(lx), __half_as_ushort(ly),
                   __half_as_ushort(lz), __half_as_ushort(lw)};
    *(ushort4*)(B2 + (size_t)row * K2 + lane * 4)       = hi4;   // coalesced
    *(ushort4*)(B2 + (size_t)row * K2 + 256 + lane * 4) = lo4;
}

// ---------------------------------------------------------------------------
// Kernel 2: z prep with transpose. z[b][e][hw] fp32 -> A2[m=b*1024+hw][k]:
// hi at k=e, lo' at k=256+e. 64hw x 64e tile through padded LDS.
// ---------------------------------------------------------------------------
__global__ __launch_bounds__(256) void k_prep_z(const float* __restrict__ z,
                                                unsigned short* __restrict__ A2) {
    __shared__ float lds[64 * 65];
    const int tid = threadIdx.x;
    const int hw0 = blockIdx.x * 64;
    const int e0  = blockIdx.y * 64;
    const int b   = blockIdx.z;
#pragma unroll
    for (int r = 0; r < 16; ++r) {
        int e  = e0 + r * 4 + (tid >> 6);
        int hw = hw0 + (tid & 63);
        lds[(tid & 63) * 65 + r * 4 + (tid >> 6)] =
            z[((size_t)b * E + e) * HW + hw];
    }
    __syncthreads();
    const int row = tid & 63;          // hw within tile
    const int q   = tid >> 6;          // 16-col group
    const size_t m = (size_t)b * HW + hw0 + row;
    unsigned short* __restrict__ ph = A2 + m * K2 + e0 + q * 16;
    unsigned short* __restrict__ pl = ph + 256;
    ushort4 hbuf[4], lbuf[4];
#pragma unroll
    for (int g = 0; g < 4; ++g) {
        float v0 = lds[row * 65 + q * 16 + g * 4 + 0];
        float v1 = lds[row * 65 + q * 16 + g * 4 + 1];
        float v2 = lds[row * 65 + q * 16 + g * 4 + 2];
        float v3 = lds[row * 65 + q * 16 + g * 4 + 3];
        __half h0 = __float2half(v0), h1 = __float2half(v1),
               h2 = __float2half(v2), h3 = __float2half(v3);
        hbuf[g] = (ushort4){__half_as_ushort(h0), __half_as_ushort(h1),
                            __half_as_ushort(h2), __half_as_ushort(h3)};
        __half l0 = __float2half((v0 - __half2float(h0)) * 4096.f);
        __half l1 = __float2half((v1 - __half2float(h1)) * 4096.f);
        __half l2 = __float2half((v2 - __half2float(h2)) * 4096.f);
        __half l3 = __float2half((v3 - __half2float(h3)) * 4096.f);
        lbuf[g] = (ushort4){__half_as_ushort(l0), __half_as_ushort(l1),
                            __half_as_ushort(l2), __half_as_ushort(l3)};
    }
#pragma unroll
    for (int g = 0; g < 4; ++g) {
        *(ushort4*)(ph + g * 4) = hbuf[g];
        *(ushort4*)(pl + g * 4) = lbuf[g];
    }
}

// ---------------------------------------------------------------------------
// Kernel 2b: init per-token argmin keys to +inf
// ---------------------------------------------------------------------------
__global__ __launch_bounds__(256) void k_init(unsigned long long* __restrict__ keys) {
    keys[blockIdx.x * 256 + threadIdx.x] = ~0ull;
}

// ---------------------------------------------------------------------------
// Kernel 3: dual-accumulator split-f16 MFMA distance GEMM + argmin.
// dot = S1 + 2^-12 * S2, S1 = hi_a.hi_b, S2 = hi_a.lo'_b + lo'_a.hi_b.
// ROUND 7 change: XOR chunk swizzle on the LDS tiles. Rows are 128 B = exactly
// 32 banks, so round 6's straight layout gave every 16-lane quad the same
// in-row offset -> same 4 banks -> 16-way conflicts (SQ_LDS_BANK_CONFLICT
// 5.03e7, LDS pipe was the bottleneck). Physical chunk p of row r now holds
// logical chunk p ^ (r&7); on the read side row&7 == lane&7, so the quad's
// 16 lanes spread across all 8 chunks (2 lanes/bank = free, m136).
// Swizzle is applied on the GLOBAL address side of global_load_lds (LDS dst
// must stay base + lane*16); global reads stay within the same 128 B segment
// -> still fully coalesced.
// ---------------------------------------------------------------------------
__global__ __launch_bounds__(256) void k_mfma(
    const unsigned short* __restrict__ A2, const unsigned short* __restrict__ B2,
    const float* __restrict__ cnorm, unsigned long long* __restrict__ keys)
{
    __shared__ __align__(16) unsigned short Ah[128 * 64];   // 16 KB each
    __shared__ __align__(16) unsigned short Al[128 * 64];
    __shared__ __align__(16) unsigned short Bh[128 * 64];
    __shared__ __align__(16) unsigned short Bl[128 * 64];

    const int tid  = threadIdx.x;
    const int lane = tid & 63;
    const int wave = __builtin_amdgcn_readfirstlane(tid >> 6);
    const int m0 = blockIdx.x * 128;
    const int n0 = blockIdx.y * 128;
    const int wm = (wave >> 1) * 64;     // wave's row block
    const int wn = (wave & 1) * 64;      // wave's col block

    const int srow  = (lane >> 3);                        // staging sub-row 0..7
    const int schnk = (((lane & 7) ^ srow) * 16);         // SWIZZLED global chunk

    f32x4 acc1[4][4], acc2[4][4];
#pragma unroll
    for (int i = 0; i < 4; ++i)
#pragma unroll
        for (int j = 0; j < 4; ++j) {
            acc1[i][j] = (f32x4){0.f, 0.f, 0.f, 0.f};
            acc2[i][j] = (f32x4){0.f, 0.f, 0.f, 0.f};
        }

    for (int kc = 0; kc < 4; ++kc) {     // four 64-half slices of E=256
        const int kb = kc * 128;         // byte offset of hi slice in a row
        // ---- stage Ah/Al/Bh/Bl: 16 wave-instrs, 8 rows each ---------------
#pragma unroll
        for (int t = 0; t < 4; ++t) {
            int r = wave * 32 + t * 8 + srow;             // r&7 == srow
            const char* arow = (const char*)A2 + (size_t)(m0 + r) * 1024;
            const char* brow = (const char*)B2 + (size_t)(n0 + r) * 1024;
            size_t dofs = (size_t)(wave * 4096 + t * 1024);
            async_cp16(arow + kb + schnk,        (char*)Ah + dofs);
            async_cp16(arow + 512 + kb + schnk,  (char*)Al + dofs);
            async_cp16(brow + kb + schnk,        (char*)Bh + dofs);
            async_cp16(brow + 512 + kb + schnk,  (char*)Bl + dofs);
        }
        __syncthreads();                 // compiler drains vmcnt before barrier
        // ---- 2 MFMA k-steps over the 64-half slice ------------------------
#pragma unroll
        for (int kk = 0; kk < 2; ++kk) {
            // logical chunk = kk*4 + quad; physical = logical ^ (row&7),
            // and row&7 == lane&7 for every fragment row (wm,wn % 64 == 0).
            const int pofs = (((kk * 4 + (lane >> 4)) ^ (lane & 7)) << 3);
            f16x8 ah[4], al[4], bh[4], bl[4];
#pragma unroll
            for (int i = 0; i < 4; ++i) {
                int ra = (wm + i * 16 + (lane & 15)) * 64 + pofs;
                ah[i] = *(const f16x8*)&Ah[ra];
                al[i] = *(const f16x8*)&Al[ra];
            }
#pragma unroll
            for (int j = 0; j < 4; ++j) {
                int rb = (wn + j * 16 + (lane & 15)) * 64 + pofs;
                bh[j] = *(const f16x8*)&Bh[rb];
                bl[j] = *(const f16x8*)&Bl[rb];
            }
#pragma unroll
            for (int i = 0; i < 4; ++i)
#pragma unroll
                for (int j = 0; j < 4; ++j) {
                    acc1[i][j] = __builtin_amdgcn_mfma_f32_16x16x32_f16(
                        ah[i], bh[j], acc1[i][j], 0, 0, 0);
                    acc2[i][j] = __builtin_amdgcn_mfma_f32_16x16x32_f16(
                        ah[i], bl[j], acc2[i][j], 0, 0, 0);
                    acc2[i][j] = __builtin_amdgcn_mfma_f32_16x16x32_f16(
                        al[i], bh[j], acc2[i][j], 0, 0, 0);
                }
        }
        __syncthreads();
    }

    // ---- epilogue: per-row argmin, C/D layout col=lane&15, row=quad*4+reg --
#pragma unroll
    for (int i = 0; i < 4; ++i) {
#pragma unroll
        for (int r = 0; r < 4; ++r) {
            int token = m0 + wm + i * 16 + ((lane >> 4) << 2) + r;
            unsigned long long best = ~0ull;
#pragma unroll
            for (int j = 0; j < 4; ++j) {
                int n = n0 + wn + j * 16 + (lane & 15);
                float dot = fmaf(acc2[i][j][r], 0x1p-12f, acc1[i][j][r]);
                float d   = fmaf(-2.f, dot, cnorm[n]);
                unsigned long long key =
                    ((unsigned long long)f2key(d) << 32) | (unsigned int)n;
                best = key < best ? key : best;
            }
#pragma unroll
            for (int off = 1; off < 16; off <<= 1) {
                unsigned long long o = __shfl_xor(best, off, 64);
                best = o < best ? o : best;
            }
            if ((lane & 15) == 0) atomicMin(&keys[token], best);
        }
    }
}

// ---------------------------------------------------------------------------
// Kernel 4: gather codebook rows -> out[B,E,H,W], LDS transpose (pad 257).
// ---------------------------------------------------------------------------
__global__ __launch_bounds__(256) void k_out(const float* __restrict__ z,
                                             const float* __restrict__ cb,
                                             const unsigned long long* __restrict__ keys,
                                             float* __restrict__ out) {
    __shared__ float xq[32 * 257];
    const int tid  = threadIdx.x;
    const int tile = blockIdx.x;                // 0..255
    const int b    = tile >> 5;
    const int hw0  = (tile & 31) << 5;          // 32 tokens per block
#pragma unroll
    for (int r = 0; r < 32; ++r) {
        int code = (int)(keys[b * HW + hw0 + r] & 0xffffffffull);  // uniform
        xq[r * 257 + tid] = cb[(size_t)code * E + tid];            // coalesced
    }
    __syncthreads();
    const int grp = tid >> 5, l = tid & 31;
#pragma unroll
    for (int j = 0; j < 32; ++j) {
        int e = grp * 32 + j;
        size_t o = (size_t)b * (E * HW) + (size_t)e * HW + hw0 + l;
        float x = z[o];
        out[o] = x + (xq[l * 257 + e] - x);
    }
}

// ---------------------------------------------------------------------------
extern "C" void kernel_launch(void* const* d_in, const int* in_sizes, int n_in,
                              void* d_out, int out_size, void* d_ws, size_t ws_size,
                              hipStream_t stream) {
    const float* z  = (const float*)d_in[0];    // [8,256,32,32]
    const float* cb = (const float*)d_in[1];    // [16384,256]
    float* out = (float*)d_out;

    // workspace layout (bytes):
    //   A2   : 8192*512*2  = 8 MB   @ 0
    //   B2   : 16384*512*2 = 16 MB  @ 8M
    //   cnorm: 64 KB                @ 24M
    //   keys : 64 KB                @ 24M+64K
    char* ws = (char*)d_ws;
    unsigned short* A2 = (unsigned short*)ws;
    unsigned short* B2 = (unsigned short*)(ws + (size_t)NTOK * K2 * 2);
    float* cnorm = (float*)(ws + (size_t)NTOK * K2 * 2 + (size_t)NE * K2 * 2);
    unsigned long long* keys = (unsigned long long*)((char*)cnorm + NE * 4);

    k_prep_cb<<<NE / 4, 256, 0, stream>>>(cb, B2, cnorm);
    k_prep_z <<<dim3(16, 4, 8), 256, 0, stream>>>(z, A2);
    k_init   <<<NTOK / 256, 256, 0, stream>>>(keys);
    k_mfma   <<<dim3(NTOK / 128, NE / 128), 256, 0, stream>>>(A2, B2, cnorm, keys);
    k_out    <<<NTOK / 32, 256, 0, stream>>>(z, cb, keys, out);
}

// Round 8
// 430.903 us; speedup vs baseline: 8.1366x; 1.1726x over previous
//
#include <hip/hip_runtime.h>
#include <hip/hip_fp16.h>
#include <math.h>

// Problem constants
#define E     256
#define HW    1024               // 32*32
#define NTOK  8192               // B*H*W
#define NE    16384
#define K2    512                // row layout: [hi(256) | lo'(256)], lo' = (x-hi)*2^12

typedef __attribute__((ext_vector_type(8))) _Float16 f16x8;
typedef __attribute__((ext_vector_type(4))) float    f32x4;

typedef __attribute__((address_space(3))) unsigned int       as3_u32;
typedef const __attribute__((address_space(1))) unsigned int as1_u32;

// async 16B/lane global->LDS: LDS dest = wave-uniform base + lane*16
static __device__ __forceinline__ void async_cp16(const void* g, void* l) {
    __builtin_amdgcn_global_load_lds((as1_u32*)g, (as3_u32*)l, 16, 0, 0);
}

// float -> order-preserving uint32 (no NaNs here)
__device__ __forceinline__ unsigned int f2key(float f) {
    unsigned int u = __float_as_uint(f);
    return (u & 0x80000000u) ? ~u : (u | 0x80000000u);
}

// ---------------------------------------------------------------------------
// Kernel 1: codebook prep. Wave per row: cnorm[n] = sum(c^2) (fp32), and
// split row: B2[n][k]=hi(c_k), B2[n][256+k]=f16((c_k-hi)*4096), K-contiguous.
// ---------------------------------------------------------------------------
__global__ __launch_bounds__(256) void k_prep_cb(const float* __restrict__ cb,
                                                 unsigned short* __restrict__ B2,
                                                 float* __restrict__ cnorm) {
    const int wid  = threadIdx.x >> 6;
    const int lane = threadIdx.x & 63;
    const int row  = blockIdx.x * 4 + wid;
    float4 v = *(const float4*)(cb + (size_t)row * E + lane * 4);
    float s = v.x * v.x + v.y * v.y + v.z * v.z + v.w * v.w;
#pragma unroll
    for (int off = 32; off >= 1; off >>= 1) s += __shfl_xor(s, off, 64);
    if (lane == 0) cnorm[row] = s;

    __half hx = __float2half(v.x), hy = __float2half(v.y),
           hz = __float2half(v.z), hw = __float2half(v.w);
    __half lx = __float2half((v.x - __half2float(hx)) * 4096.f);
    __half ly = __float2half((v.y - __half2float(hy)) * 4096.f);
    __half lz = __float2half((v.z - __half2float(hz)) * 4096.f);
    __half lw = __float2half((v.w - __half2float(hw)) * 4096.f);
    ushort4 hi4 = {__half_as_ushort(hx), __half_as_ushort(hy),
                   __half_as_ushort(hz), __half_as_ushort(hw)};
    ushort4 lo4 = {__half_as_ushort(lx), __half_as_ushort(ly),
                   __half_as_ushort(lz), __half_as_ushort(lw)};
    *(ushort4*)(B2 + (size_t)row * K2 + lane * 4)       = hi4;   // coalesced
    *(ushort4*)(B2 + (size_t)row * K2 + 256 + lane * 4) = lo4;
}

// ---------------------------------------------------------------------------
// Kernel 2: z prep with transpose. z[b][e][hw] fp32 -> A2[m=b*1024+hw][k]:
// hi at k=e, lo' at k=256+e. 64hw x 64e tile through padded LDS.
// ---------------------------------------------------------------------------
__global__ __launch_bounds__(256) void k_prep_z(const float* __restrict__ z,
                                                unsigned short* __restrict__ A2) {
    __shared__ float lds[64 * 65];
    const int tid = threadIdx.x;
    const int hw0 = blockIdx.x * 64;
    const int e0  = blockIdx.y * 64;
    const int b   = blockIdx.z;
#pragma unroll
    for (int r = 0; r < 16; ++r) {
        int e  = e0 + r * 4 + (tid >> 6);
        int hw = hw0 + (tid & 63);
        lds[(tid & 63) * 65 + r * 4 + (tid >> 6)] =
            z[((size_t)b * E + e) * HW + hw];
    }
    __syncthreads();
    const int row = tid & 63;          // hw within tile
    const int q   = tid >> 6;          // 16-col group
    const size_t m = (size_t)b * HW + hw0 + row;
    unsigned short* __restrict__ ph = A2 + m * K2 + e0 + q * 16;
    unsigned short* __restrict__ pl = ph + 256;
    ushort4 hbuf[4], lbuf[4];
#pragma unroll
    for (int g = 0; g < 4; ++g) {
        float v0 = lds[row * 65 + q * 16 + g * 4 + 0];
        float v1 = lds[row * 65 + q * 16 + g * 4 + 1];
        float v2 = lds[row * 65 + q * 16 + g * 4 + 2];
        float v3 = lds[row * 65 + q * 16 + g * 4 + 3];
        __half h0 = __float2half(v0), h1 = __float2half(v1),
               h2 = __float2half(v2), h3 = __float2half(v3);
        hbuf[g] = (ushort4){__half_as_ushort(h0), __half_as_ushort(h1),
                            __half_as_ushort(h2), __half_as_ushort(h3)};
        __half l0 = __float2half((v0 - __half2float(h0)) * 4096.f);
        __half l1 = __float2half((v1 - __half2float(h1)) * 4096.f);
        __half l2 = __float2half((v2 - __half2float(h2)) * 4096.f);
        __half l3 = __float2half((v3 - __half2float(h3)) * 4096.f);
        lbuf[g] = (ushort4){__half_as_ushort(l0), __half_as_ushort(l1),
                            __half_as_ushort(l2), __half_as_ushort(l3)};
    }
#pragma unroll
    for (int g = 0; g < 4; ++g) {
        *(ushort4*)(ph + g * 4) = hbuf[g];
        *(ushort4*)(pl + g * 4) = lbuf[g];
    }
}

// ---------------------------------------------------------------------------
// Kernel 2b: init per-token argmin keys to +inf
// ---------------------------------------------------------------------------
__global__ __launch_bounds__(256) void k_init(unsigned long long* __restrict__ keys) {
    keys[blockIdx.x * 256 + threadIdx.x] = ~0ull;
}

// ---------------------------------------------------------------------------
// Kernel 3: dual-accumulator split-f16 MFMA distance GEMM + argmin.
// dot = S1 + 2^-12 * S2, S1 = hi_a.hi_b, S2 = hi_a.lo'_b + lo'_a.hi_b.
// ROUND 8 change: BK 64 -> 32 halves. Round 7 ran at 1 block/CU
// (OccupancyPercent 11.8, LDS 64KB) -> zero inter-block overlap, so every
// barrier's vmcnt(0) drain was dead time (465us vs ~100us of MFMA work;
// killing all bank conflicts moved nothing). 32KB LDS + launch_bounds(256,3)
// -> 3 blocks/CU; resident blocks' MFMA hides other blocks' staging drains
// (m114 overlap model). Same totals of MFMA/ds_read per block; summation
// order bit-identical (8 sequential K=32 accumulations per acc either way).
// Swizzle reworked for 64B rows / 4 chunks: physical chunk p = q ^ (r&3),
// read side p = (lane>>4) ^ (lane&3) -> 2 lanes/bank (free, m136).
// ---------------------------------------------------------------------------
__global__ __launch_bounds__(256, 3) void k_mfma(
    const unsigned short* __restrict__ A2, const unsigned short* __restrict__ B2,
    const float* __restrict__ cnorm, unsigned long long* __restrict__ keys)
{
    __shared__ __align__(16) unsigned short Ah[128 * 32];   // 8 KB each
    __shared__ __align__(16) unsigned short Al[128 * 32];
    __shared__ __align__(16) unsigned short Bh[128 * 32];
    __shared__ __align__(16) unsigned short Bl[128 * 32];

    const int tid  = threadIdx.x;
    const int lane = tid & 63;
    const int wave = __builtin_amdgcn_readfirstlane(tid >> 6);
    const int m0 = blockIdx.x * 128;
    const int n0 = blockIdx.y * 128;
    const int wm = (wave >> 1) * 64;     // wave's row block
    const int wn = (wave & 1) * 64;      // wave's col block

    const int srow  = (lane >> 2);                        // staging row 0..15
    const int schnk = (((lane & 3) ^ (srow & 3)) * 16);   // SWIZZLED logical chunk

    f32x4 acc1[4][4], acc2[4][4];
#pragma unroll
    for (int i = 0; i < 4; ++i)
#pragma unroll
        for (int j = 0; j < 4; ++j) {
            acc1[i][j] = (f32x4){0.f, 0.f, 0.f, 0.f};
            acc2[i][j] = (f32x4){0.f, 0.f, 0.f, 0.f};
        }

    // fragment read offset: logical chunk lane>>4, physical = ^ (row&3),
    // row&3 == lane&3 for all fragment rows (wm,wn,i*16 are mult of 4).
    const int pofs = (((lane >> 4) ^ (lane & 3)) << 4);   // byte offset in row

    for (int kc = 0; kc < 8; ++kc) {     // eight 32-half slices of E=256
        const int kb = kc * 64;          // byte offset of hi slice in a row
        // ---- stage Ah/Al/Bh/Bl: 8 wave-instrs, 16 rows each ---------------
#pragma unroll
        for (int t = 0; t < 2; ++t) {
            int r = wave * 32 + t * 16 + srow;            // r&3 == srow&3
            const char* arow = (const char*)A2 + (size_t)(m0 + r) * 1024;
            const char* brow = (const char*)B2 + (size_t)(n0 + r) * 1024;
            size_t dofs = (size_t)(wave * 2048 + t * 1024);
            async_cp16(arow + kb + schnk,        (char*)Ah + dofs);
            async_cp16(arow + 512 + kb + schnk,  (char*)Al + dofs);
            async_cp16(brow + kb + schnk,        (char*)Bh + dofs);
            async_cp16(brow + 512 + kb + schnk,  (char*)Bl + dofs);
        }
        __syncthreads();                 // compiler drains vmcnt before barrier
        // ---- one MFMA k-step (K=32 halves) --------------------------------
        f16x8 ah[4], al[4], bh[4], bl[4];
#pragma unroll
        for (int i = 0; i < 4; ++i) {
            int ra = (wm + i * 16 + (lane & 15)) * 64 + pofs;   // byte offset
            ah[i] = *(const f16x8*)((const char*)Ah + ra);
            al[i] = *(const f16x8*)((const char*)Al + ra);
        }
#pragma unroll
        for (int j = 0; j < 4; ++j) {
            int rb = (wn + j * 16 + (lane & 15)) * 64 + pofs;
            bh[j] = *(const f16x8*)((const char*)Bh + rb);
            bl[j] = *(const f16x8*)((const char*)Bl + rb);
        }
        // three passes; the two acc2 contributions stay in (bl, then bh)
        // order per accumulator but are separated by 16 independent MFMAs.
#pragma unroll
        for (int i = 0; i < 4; ++i)
#pragma unroll
            for (int j = 0; j < 4; ++j)
                acc2[i][j] = __builtin_amdgcn_mfma_f32_16x16x32_f16(
                    ah[i], bl[j], acc2[i][j], 0, 0, 0);
#pragma unroll
        for (int i = 0; i < 4; ++i)
#pragma unroll
            for (int j = 0; j < 4; ++j)
                acc1[i][j] = __builtin_amdgcn_mfma_f32_16x16x32_f16(
                    ah[i], bh[j], acc1[i][j], 0, 0, 0);
#pragma unroll
        for (int i = 0; i < 4; ++i)
#pragma unroll
            for (int j = 0; j < 4; ++j)
                acc2[i][j] = __builtin_amdgcn_mfma_f32_16x16x32_f16(
                    al[i], bh[j], acc2[i][j], 0, 0, 0);
        __syncthreads();
    }

    // ---- epilogue: per-row argmin, C/D layout col=lane&15, row=quad*4+reg --
#pragma unroll
    for (int i = 0; i < 4; ++i) {
#pragma unroll
        for (int r = 0; r < 4; ++r) {
            int token = m0 + wm + i * 16 + ((lane >> 4) << 2) + r;
            unsigned long long best = ~0ull;
#pragma unroll
            for (int j = 0; j < 4; ++j) {
                int n = n0 + wn + j * 16 + (lane & 15);
                float dot = fmaf(acc2[i][j][r], 0x1p-12f, acc1[i][j][r]);
                float d   = fmaf(-2.f, dot, cnorm[n]);
                unsigned long long key =
                    ((unsigned long long)f2key(d) << 32) | (unsigned int)n;
                best = key < best ? key : best;
            }
#pragma unroll
            for (int off = 1; off < 16; off <<= 1) {
                unsigned long long o = __shfl_xor(best, off, 64);
                best = o < best ? o : best;
            }
            if ((lane & 15) == 0) atomicMin(&keys[token], best);
        }
    }
}

// ---------------------------------------------------------------------------
// Kernel 4: gather codebook rows -> out[B,E,H,W], LDS transpose (pad 257).
// ---------------------------------------------------------------------------
__global__ __launch_bounds__(256) void k_out(const float* __restrict__ z,
                                             const float* __restrict__ cb,
                                             const unsigned long long* __restrict__ keys,
                                             float* __restrict__ out) {
    __shared__ float xq[32 * 257];
    const int tid  = threadIdx.x;
    const int tile = blockIdx.x;                // 0..255
    const int b    = tile >> 5;
    const int hw0  = (tile & 31) << 5;          // 32 tokens per block
#pragma unroll
    for (int r = 0; r < 32; ++r) {
        int code = (int)(keys[b * HW + hw0 + r] & 0xffffffffull);  // uniform
        xq[r * 257 + tid] = cb[(size_t)code * E + tid];            // coalesced
    }
    __syncthreads();
    const int grp = tid >> 5, l = tid & 31;
#pragma unroll
    for (int j = 0; j < 32; ++j) {
        int e = grp * 32 + j;
        size_t o = (size_t)b * (E * HW) + (size_t)e * HW + hw0 + l;
        float x = z[o];
        out[o] = x + (xq[l * 257 + e] - x);
    }
}

// ---------------------------------------------------------------------------
extern "C" void kernel_launch(void* const* d_in, const int* in_sizes, int n_in,
                              void* d_out, int out_size, void* d_ws, size_t ws_size,
                              hipStream_t stream) {
    const float* z  = (const float*)d_in[0];    // [8,256,32,32]
    const float* cb = (const float*)d_in[1];    // [16384,256]
    float* out = (float*)d_out;

    // workspace layout (bytes):
    //   A2   : 8192*512*2  = 8 MB   @ 0
    //   B2   : 16384*512*2 = 16 MB  @ 8M
    //   cnorm: 64 KB                @ 24M
    //   keys : 64 KB                @ 24M+64K
    char* ws = (char*)d_ws;
    unsigned short* A2 = (unsigned short*)ws;
    unsigned short* B2 = (unsigned short*)(ws + (size_t)NTOK * K2 * 2);
    float* cnorm = (float*)(ws + (size_t)NTOK * K2 * 2 + (size_t)NE * K2 * 2);
    unsigned long long* keys = (unsigned long long*)((char*)cnorm + NE * 4);

    k_prep_cb<<<NE / 4, 256, 0, stream>>>(cb, B2, cnorm);
    k_prep_z <<<dim3(16, 4, 8), 256, 0, stream>>>(z, A2);
    k_init   <<<NTOK / 256, 256, 0, stream>>>(keys);
    k_mfma   <<<dim3(NTOK / 128, NE / 128), 256, 0, stream>>>(A2, B2, cnorm, keys);
    k_out    <<<NTOK / 32, 256, 0, stream>>>(z, cb, keys, out);
}

// Round 9
// 414.591 us; speedup vs baseline: 8.4568x; 1.0393x over previous
//
#include <hip/hip_runtime.h>
#include <hip/hip_fp16.h>
#include <math.h>

// Problem constants
#define E     256
#define HW    1024               // 32*32
#define NTOK  8192               // B*H*W
#define NE    16384
#define K2    512                // row layout: [hi(256) | lo'(256)], lo' = (x-hi)*2^12

typedef __attribute__((ext_vector_type(8))) _Float16 f16x8;
typedef __attribute__((ext_vector_type(4))) float    f32x4;

typedef __attribute__((address_space(3))) unsigned int       as3_u32;
typedef const __attribute__((address_space(1))) unsigned int as1_u32;

// async 16B/lane global->LDS: LDS dest = wave-uniform base + lane*16
static __device__ __forceinline__ void async_cp16(const void* g, void* l) {
    __builtin_amdgcn_global_load_lds((as1_u32*)g, (as3_u32*)l, 16, 0, 0);
}

// float -> order-preserving uint32 (no NaNs here)
__device__ __forceinline__ unsigned int f2key(float f) {
    unsigned int u = __float_as_uint(f);
    return (u & 0x80000000u) ? ~u : (u | 0x80000000u);
}

// ---------------------------------------------------------------------------
// Kernel 1: codebook prep. Wave per row: cnorm[n] = sum(c^2) (fp32), and
// split row: B2[n][k]=hi(c_k), B2[n][256+k]=f16((c_k-hi)*4096), K-contiguous.
// ---------------------------------------------------------------------------
__global__ __launch_bounds__(256) void k_prep_cb(const float* __restrict__ cb,
                                                 unsigned short* __restrict__ B2,
                                                 float* __restrict__ cnorm) {
    const int wid  = threadIdx.x >> 6;
    const int lane = threadIdx.x & 63;
    const int row  = blockIdx.x * 4 + wid;
    float4 v = *(const float4*)(cb + (size_t)row * E + lane * 4);
    float s = v.x * v.x + v.y * v.y + v.z * v.z + v.w * v.w;
#pragma unroll
    for (int off = 32; off >= 1; off >>= 1) s += __shfl_xor(s, off, 64);
    if (lane == 0) cnorm[row] = s;

    __half hx = __float2half(v.x), hy = __float2half(v.y),
           hz = __float2half(v.z), hw = __float2half(v.w);
    __half lx = __float2half((v.x - __half2float(hx)) * 4096.f);
    __half ly = __float2half((v.y - __half2float(hy)) * 4096.f);
    __half lz = __float2half((v.z - __half2float(hz)) * 4096.f);
    __half lw = __float2half((v.w - __half2float(hw)) * 4096.f);
    ushort4 hi4 = {__half_as_ushort(hx), __half_as_ushort(hy),
                   __half_as_ushort(hz), __half_as_ushort(hw)};
    ushort4 lo4 = {__half_as_ushort(lx), __half_as_ushort(ly),
                   __half_as_ushort(lz), __half_as_ushort(lw)};
    *(ushort4*)(B2 + (size_t)row * K2 + lane * 4)       = hi4;   // coalesced
    *(ushort4*)(B2 + (size_t)row * K2 + 256 + lane * 4) = lo4;
}

// ---------------------------------------------------------------------------
// Kernel 2: z prep with transpose. z[b][e][hw] fp32 -> A2[m=b*1024+hw][k]:
// hi at k=e, lo' at k=256+e. 64hw x 64e tile through padded LDS.
// ---------------------------------------------------------------------------
__global__ __launch_bounds__(256) void k_prep_z(const float* __restrict__ z,
                                                unsigned short* __restrict__ A2) {
    __shared__ float lds[64 * 65];
    const int tid = threadIdx.x;
    const int hw0 = blockIdx.x * 64;
    const int e0  = blockIdx.y * 64;
    const int b   = blockIdx.z;
#pragma unroll
    for (int r = 0; r < 16; ++r) {
        int e  = e0 + r * 4 + (tid >> 6);
        int hw = hw0 + (tid & 63);
        lds[(tid & 63) * 65 + r * 4 + (tid >> 6)] =
            z[((size_t)b * E + e) * HW + hw];
    }
    __syncthreads();
    const int row = tid & 63;          // hw within tile
    const int q   = tid >> 6;          // 16-col group
    const size_t m = (size_t)b * HW + hw0 + row;
    unsigned short* __restrict__ ph = A2 + m * K2 + e0 + q * 16;
    unsigned short* __restrict__ pl = ph + 256;
    ushort4 hbuf[4], lbuf[4];
#pragma unroll
    for (int g = 0; g < 4; ++g) {
        float v0 = lds[row * 65 + q * 16 + g * 4 + 0];
        float v1 = lds[row * 65 + q * 16 + g * 4 + 1];
        float v2 = lds[row * 65 + q * 16 + g * 4 + 2];
        float v3 = lds[row * 65 + q * 16 + g * 4 + 3];
        __half h0 = __float2half(v0), h1 = __float2half(v1),
               h2 = __float2half(v2), h3 = __float2half(v3);
        hbuf[g] = (ushort4){__half_as_ushort(h0), __half_as_ushort(h1),
                            __half_as_ushort(h2), __half_as_ushort(h3)};
        __half l0 = __float2half((v0 - __half2float(h0)) * 4096.f);
        __half l1 = __float2half((v1 - __half2float(h1)) * 4096.f);
        __half l2 = __float2half((v2 - __half2float(h2)) * 4096.f);
        __half l3 = __float2half((v3 - __half2float(h3)) * 4096.f);
        lbuf[g] = (ushort4){__half_as_ushort(l0), __half_as_ushort(l1),
                            __half_as_ushort(l2), __half_as_ushort(l3)};
    }
#pragma unroll
    for (int g = 0; g < 4; ++g) {
        *(ushort4*)(ph + g * 4) = hbuf[g];
        *(ushort4*)(pl + g * 4) = lbuf[g];
    }
}

// ---------------------------------------------------------------------------
// Kernel 2b: init per-token argmin keys to +inf
// ---------------------------------------------------------------------------
__global__ __launch_bounds__(256) void k_init(unsigned long long* __restrict__ keys) {
    keys[blockIdx.x * 256 + threadIdx.x] = ~0ull;
}

// ---------------------------------------------------------------------------
// Kernel 3: dual-accumulator split-f16 MFMA distance GEMM + argmin.
// dot = S1 + 2^-12 * S2, S1 = hi_a.hi_b, S2 = hi_a.lo'_b + lo'_a.hi_b.
// ROUND 9 changes (round 8 hit 387us with three self-inflicted wounds):
//  (a) CORRECT swizzle for 64B rows. Row r starts at bank 16*(r&1), so the
//      spread bit is r>>1: physical chunk p = q ^ ((r>>1)&3). Read side:
//      pofs = ((lane>>4) ^ ((lane>>1)&3))<<4 -> each 16-lane quad covers all
//      8 four-bank groups, 2 lanes each (free). Round 8's p = q ^ (r&3) gave
//      4-way conflicts (SQ_LDS_BANK_CONFLICT 1.7e7).
//  (b) launch_bounds(256,2): round 8's (256,3) capped regs at 170 < ~217
//      natural (acc 128 + frags 64) -> VGPR_Count 84 + massive scratch spill
//      (599 MB WRITE_SIZE). 256-reg cap fits -> no spill, 2 blocks/CU.
//  (c) XCD-aware 1-D grid decode: xcd = bid&7 owns n-chunks [xcd*16,+16),
//      x-slowest within XCD -> per-XCD L2 working set ~2.6 MB (fits 4 MB);
//      B2 fetched ~once per XCD. Round 8 streamed B2 through every XCD's L2
//      (FETCH 280 MB, staging drains at HBM latency ~900cyc not L2 ~200).
// ---------------------------------------------------------------------------
__global__ __launch_bounds__(256, 2) void k_mfma(
    const unsigned short* __restrict__ A2, const unsigned short* __restrict__ B2,
    const float* __restrict__ cnorm, unsigned long long* __restrict__ keys)
{
    __shared__ __align__(16) unsigned short Ah[128 * 32];   // 8 KB each
    __shared__ __align__(16) unsigned short Al[128 * 32];
    __shared__ __align__(16) unsigned short Bh[128 * 32];
    __shared__ __align__(16) unsigned short Bl[128 * 32];

    const int tid  = threadIdx.x;
    const int lane = tid & 63;
    const int wave = __builtin_amdgcn_readfirstlane(tid >> 6);

    // XCD-aware decode: 8192 blocks; xcd=bid&7 -> n-chunk range, x slowest.
    const int bid   = blockIdx.x;
    const int xcd   = bid & 7;
    const int loc   = bid >> 3;          // 0..1023 within XCD
    const int xtile = loc >> 4;          // 0..63  (token tile, slowest)
    const int ytile = xcd * 16 + (loc & 15);   // 0..127 (code chunk)
    const int m0 = xtile * 128;
    const int n0 = ytile * 128;

    const int wm = (wave >> 1) * 64;     // wave's row block
    const int wn = (wave & 1) * 64;      // wave's col block

    const int srow  = (lane >> 2);                        // staging row 0..15
    const int schnk = (((lane & 3) ^ ((lane >> 3) & 3)) * 16);  // swizzled src chunk

    f32x4 acc1[4][4], acc2[4][4];
#pragma unroll
    for (int i = 0; i < 4; ++i)
#pragma unroll
        for (int j = 0; j < 4; ++j) {
            acc1[i][j] = (f32x4){0.f, 0.f, 0.f, 0.f};
            acc2[i][j] = (f32x4){0.f, 0.f, 0.f, 0.f};
        }

    // fragment read: logical chunk lane>>4, physical = ^ ((row>>1)&3);
    // (row>>1)&3 == (lane>>1)&3 for fragment rows (base multiple of 16).
    const int pofs = (((lane >> 4) ^ ((lane >> 1) & 3)) << 4);   // byte in row

    for (int kc = 0; kc < 8; ++kc) {     // eight 32-half slices of E=256
        const int kb = kc * 64;          // byte offset of hi slice in a row
        // ---- stage Ah/Al/Bh/Bl: 8 wave-instrs, 16 rows each ---------------
#pragma unroll
        for (int t = 0; t < 2; ++t) {
            int r = wave * 32 + t * 16 + srow;            // (r>>1)&3 == (lane>>3)&3
            const char* arow = (const char*)A2 + (size_t)(m0 + r) * 1024;
            const char* brow = (const char*)B2 + (size_t)(n0 + r) * 1024;
            size_t dofs = (size_t)(wave * 2048 + t * 1024);
            async_cp16(arow + kb + schnk,        (char*)Ah + dofs);
            async_cp16(arow + 512 + kb + schnk,  (char*)Al + dofs);
            async_cp16(brow + kb + schnk,        (char*)Bh + dofs);
            async_cp16(brow + 512 + kb + schnk,  (char*)Bl + dofs);
        }
        __syncthreads();                 // compiler drains vmcnt before barrier
        // ---- one MFMA k-step (K=32 halves) --------------------------------
        f16x8 ah[4], al[4], bh[4], bl[4];
#pragma unroll
        for (int i = 0; i < 4; ++i) {
            int ra = (wm + i * 16 + (lane & 15)) * 64 + pofs;   // byte offset
            ah[i] = *(const f16x8*)((const char*)Ah + ra);
            al[i] = *(const f16x8*)((const char*)Al + ra);
        }
#pragma unroll
        for (int j = 0; j < 4; ++j) {
            int rb = (wn + j * 16 + (lane & 15)) * 64 + pofs;
            bh[j] = *(const f16x8*)((const char*)Bh + rb);
            bl[j] = *(const f16x8*)((const char*)Bl + rb);
        }
        // three passes; acc2's two contributions are separated by 16
        // independent MFMAs (latency hiding), order per-acc fixed.
#pragma unroll
        for (int i = 0; i < 4; ++i)
#pragma unroll
            for (int j = 0; j < 4; ++j)
                acc2[i][j] = __builtin_amdgcn_mfma_f32_16x16x32_f16(
                    ah[i], bl[j], acc2[i][j], 0, 0, 0);
#pragma unroll
        for (int i = 0; i < 4; ++i)
#pragma unroll
            for (int j = 0; j < 4; ++j)
                acc1[i][j] = __builtin_amdgcn_mfma_f32_16x16x32_f16(
                    ah[i], bh[j], acc1[i][j], 0, 0, 0);
#pragma unroll
        for (int i = 0; i < 4; ++i)
#pragma unroll
            for (int j = 0; j < 4; ++j)
                acc2[i][j] = __builtin_amdgcn_mfma_f32_16x16x32_f16(
                    al[i], bh[j], acc2[i][j], 0, 0, 0);
        __syncthreads();
    }

    // ---- epilogue: per-row argmin, C/D layout col=lane&15, row=quad*4+reg --
#pragma unroll
    for (int i = 0; i < 4; ++i) {
#pragma unroll
        for (int r = 0; r < 4; ++r) {
            int token = m0 + wm + i * 16 + ((lane >> 4) << 2) + r;
            unsigned long long best = ~0ull;
#pragma unroll
            for (int j = 0; j < 4; ++j) {
                int n = n0 + wn + j * 16 + (lane & 15);
                float dot = fmaf(acc2[i][j][r], 0x1p-12f, acc1[i][j][r]);
                float d   = fmaf(-2.f, dot, cnorm[n]);
                unsigned long long key =
                    ((unsigned long long)f2key(d) << 32) | (unsigned int)n;
                best = key < best ? key : best;
            }
#pragma unroll
            for (int off = 1; off < 16; off <<= 1) {
                unsigned long long o = __shfl_xor(best, off, 64);
                best = o < best ? o : best;
            }
            if ((lane & 15) == 0) atomicMin(&keys[token], best);
        }
    }
}

// ---------------------------------------------------------------------------
// Kernel 4: gather codebook rows -> out[B,E,H,W], LDS transpose (pad 257).
// ---------------------------------------------------------------------------
__global__ __launch_bounds__(256) void k_out(const float* __restrict__ z,
                                             const float* __restrict__ cb,
                                             const unsigned long long* __restrict__ keys,
                                             float* __restrict__ out) {
    __shared__ float xq[32 * 257];
    const int tid  = threadIdx.x;
    const int tile = blockIdx.x;                // 0..255
    const int b    = tile >> 5;
    const int hw0  = (tile & 31) << 5;          // 32 tokens per block
#pragma unroll
    for (int r = 0; r < 32; ++r) {
        int code = (int)(keys[b * HW + hw0 + r] & 0xffffffffull);  // uniform
        xq[r * 257 + tid] = cb[(size_t)code * E + tid];            // coalesced
    }
    __syncthreads();
    const int grp = tid >> 5, l = tid & 31;
#pragma unroll
    for (int j = 0; j < 32; ++j) {
        int e = grp * 32 + j;
        size_t o = (size_t)b * (E * HW) + (size_t)e * HW + hw0 + l;
        float x = z[o];
        out[o] = x + (xq[l * 257 + e] - x);
    }
}

// ---------------------------------------------------------------------------
extern "C" void kernel_launch(void* const* d_in, const int* in_sizes, int n_in,
                              void* d_out, int out_size, void* d_ws, size_t ws_size,
                              hipStream_t stream) {
    const float* z  = (const float*)d_in[0];    // [8,256,32,32]
    const float* cb = (const float*)d_in[1];    // [16384,256]
    float* out = (float*)d_out;

    // workspace layout (bytes):
    //   A2   : 8192*512*2  = 8 MB   @ 0
    //   B2   : 16384*512*2 = 16 MB  @ 8M
    //   cnorm: 64 KB                @ 24M
    //   keys : 64 KB                @ 24M+64K
    char* ws = (char*)d_ws;
    unsigned short* A2 = (unsigned short*)ws;
    unsigned short* B2 = (unsigned short*)(ws + (size_t)NTOK * K2 * 2);
    float* cnorm = (float*)(ws + (size_t)NTOK * K2 * 2 + (size_t)NE * K2 * 2);
    unsigned long long* keys = (unsigned long long*)((char*)cnorm + NE * 4);

    k_prep_cb<<<NE / 4, 256, 0, stream>>>(cb, B2, cnorm);
    k_prep_z <<<dim3(16, 4, 8), 256, 0, stream>>>(z, A2);
    k_init   <<<NTOK / 256, 256, 0, stream>>>(keys);
    k_mfma   <<<8192, 256, 0, stream>>>(A2, B2, cnorm, keys);
    k_out    <<<NTOK / 32, 256, 0, stream>>>(z, cb, keys, out);
}